// Round 6
// baseline (307.151 us; speedup 1.0000x reference)
//
#include <hip/hip_runtime.h>

// Problem constants (setup_inputs fixed: N=4, Lq=6400, C=256, H=W=80)
#define NB    4
#define LQ    6400
#define CC    256
#define HH    80
#define WW    80
#define HWSZ  (HH*WW)
#define RTOT  (NB*LQ)        // 25600 rows
#define HID   1024

typedef __attribute__((ext_vector_type(8))) short bf16x8;   // 8 bf16 = 4 VGPRs
typedef __attribute__((ext_vector_type(4))) float f32x4;

__device__ __forceinline__ float bf2f(unsigned short u) {
    unsigned int i = ((unsigned int)u) << 16;
    float f; __builtin_memcpy(&f, &i, 4); return f;
}
__device__ __forceinline__ unsigned short f2bf(float f) {
    unsigned int i; __builtin_memcpy(&i, &f, 4);
    unsigned int r = i + 0x7fffu + ((i >> 16) & 1u);   // RNE
    return (unsigned short)(r >> 16);
}

// ---------------- fp32 -> bf16 convert (4 elems/thread) ----------------
__global__ void cvt_k(const float* __restrict__ in, unsigned short* __restrict__ out, int n4) {
    int i = blockIdx.x * 256 + threadIdx.x;
    if (i < n4) {
        float4 u = ((const float4*)in)[i];
        ushort4 o;
        o.x = f2bf(u.x); o.y = f2bf(u.y); o.z = f2bf(u.z); o.w = f2bf(u.w);
        ((ushort4*)out)[i] = o;
    }
}

// ---------------- transpose + convert: Bt_bf16[n*K + k] = B_f32[k*N + n] ----------------
__global__ void transpose_cvt_k(const float* __restrict__ B,
                                unsigned short* __restrict__ Bt, int K, int N) {
    int idx = blockIdx.x * 256 + threadIdx.x;
    if (idx < K * N) {
        int n = idx / K;
        int k = idx - n * K;
        Bt[idx] = f2bf(B[k * N + n]);
    }
}

// ---------------- fragment-major weight swizzle ----------------
// dst group g (8 bf16): n = g%N, kq = g/N, kbase = (kq>>2)*32 + (kq&3)*8
// dst[g*8+j] = bf16(src[(kbase+j)*N + n]) — the exact VGPR image an A-fragment wants.
__global__ void swizzle_k(const float* __restrict__ src, unsigned short* __restrict__ dst,
                          int K, int N) {
    int g = blockIdx.x * 256 + threadIdx.x;
    if (g >= (K / 8) * N) return;
    int n  = g % N;
    int kq = g / N;
    int kbase = (kq >> 2) * 32 + (kq & 3) * 8;
    unsigned short* d = dst + (size_t)g * 8;
    #pragma unroll
    for (int j = 0; j < 8; ++j)
        d[j] = f2bf(src[(size_t)(kbase + j) * N + n]);
}

// ---------------- concat boff(64) + ba(32) into one fp32 bias[96] ----------------
__global__ void bias_cat_k(const float* __restrict__ boff, const float* __restrict__ ba,
                           float* __restrict__ out) {
    int i = threadIdx.x;
    if (i < 64) out[i] = boff[i];
    else if (i < 96) out[i] = ba[i - 64];
}

// ---------------- layernorm over C=256: fp32 in -> bf16 out; 1 wave/row ----------------
__global__ void ln_k(const float* __restrict__ x,
                     const float* __restrict__ w,
                     const float* __restrict__ b,
                     unsigned short* __restrict__ y) {
    int row  = blockIdx.x * 4 + (threadIdx.x >> 6);
    int lane = threadIdx.x & 63;
    const float* xr = x + (size_t)row * CC + lane * 4;
    float4 u = *(const float4*)xr;
    float s  = u.x + u.y + u.z + u.w;
    float s2 = u.x*u.x + u.y*u.y + u.z*u.z + u.w*u.w;
    #pragma unroll
    for (int m = 1; m < 64; m <<= 1) {
        s  += __shfl_xor(s,  m);
        s2 += __shfl_xor(s2, m);
    }
    float mean = s * (1.0f / CC);
    float var  = s2 * (1.0f / CC) - mean * mean;
    float rstd = rsqrtf(fmaxf(var, 0.0f) + 1e-5f);
    float4 uw = *(const float4*)(w + lane * 4);
    float4 ub = *(const float4*)(b + lane * 4);
    ushort4 o;
    o.x = f2bf((u.x - mean) * rstd * uw.x + ub.x);
    o.y = f2bf((u.y - mean) * rstd * uw.y + ub.y);
    o.z = f2bf((u.z - mean) * rstd * uw.z + ub.z);
    o.w = f2bf((u.w - mean) * rstd * uw.w + ub.w);
    *(ushort4*)(y + (size_t)row * CC + lane * 4) = o;
}

// ---------------- tiled GEMM (m97 structure) ----------------
template<int EPI, bool OF32>
__global__ __launch_bounds__(256) void gemm_t(const unsigned short* __restrict__ A,
                                              const unsigned short* __restrict__ Bt,
                                              const float* __restrict__ bias,
                                              const float* __restrict__ res,
                                              void* __restrict__ Cout_,
                                              int M, int Nv, int K) {
    __shared__ unsigned short Als[128 * 32];
    __shared__ unsigned short Bls[128 * 32];
    int lane = threadIdx.x & 63;
    int wave = threadIdx.x >> 6;
    int quad = lane >> 4;
    int l16  = lane & 15;
    int m0 = blockIdx.x * 128;
    int n0 = blockIdx.y * 128;
    int wm = (wave & 1) * 64;
    int wn = (wave >> 1) * 64;

    f32x4 acc[4][4];
    #pragma unroll
    for (int i = 0; i < 4; ++i)
        #pragma unroll
        for (int j = 0; j < 4; ++j)
            acc[i][j] = (f32x4){0.f, 0.f, 0.f, 0.f};

    int srow = lane >> 2;
    int scol = (lane & 3) * 8;
    const unsigned short* Ag = A  + (size_t)(m0 + wave * 32 + srow) * K + scol;
    const unsigned short* Bg = Bt + (size_t)(n0 + wave * 32 + srow) * K + scol;
    unsigned short* Alp = &Als[wave * 1024];
    unsigned short* Blp = &Bls[wave * 1024];

    for (int k0 = 0; k0 < K; k0 += 32) {
        __syncthreads();
        #pragma unroll
        for (int t = 0; t < 2; ++t) {
            __builtin_amdgcn_global_load_lds(
                (const __attribute__((address_space(1))) void*)(Ag + (size_t)t * 16 * K + k0),
                (__attribute__((address_space(3))) void*)(Alp + t * 512), 16, 0, 0);
            __builtin_amdgcn_global_load_lds(
                (const __attribute__((address_space(1))) void*)(Bg + (size_t)t * 16 * K + k0),
                (__attribute__((address_space(3))) void*)(Blp + t * 512), 16, 0, 0);
        }
        __builtin_amdgcn_s_waitcnt(0);
        __syncthreads();

        bf16x8 af[4], bfr[4];
        #pragma unroll
        for (int i = 0; i < 4; ++i)
            af[i] = *(const bf16x8*)&Als[(wm + i * 16 + l16) * 32 + quad * 8];
        #pragma unroll
        for (int j = 0; j < 4; ++j)
            bfr[j] = *(const bf16x8*)&Bls[(wn + j * 16 + l16) * 32 + quad * 8];
        #pragma unroll
        for (int i = 0; i < 4; ++i)
            #pragma unroll
            for (int j = 0; j < 4; ++j)
                acc[i][j] = __builtin_amdgcn_mfma_f32_16x16x32_bf16(af[i], bfr[j], acc[i][j], 0, 0, 0);
    }

    #pragma unroll
    for (int j = 0; j < 4; ++j) {
        int cbase = n0 + wn + j * 16;
        if (cbase >= Nv) continue;
        int col = cbase + l16;
        float bv = bias[col];
        #pragma unroll
        for (int i = 0; i < 4; ++i) {
            #pragma unroll
            for (int r = 0; r < 4; ++r) {
                int row = m0 + wm + i * 16 + quad * 4 + r;
                float val = acc[i][j][r] + bv;
                if (EPI == 1) val = 0.5f * val * (1.0f + erff(val * 0.70710678118654752f));
                if (EPI == 2) val += res[(size_t)row * Nv + col];
                if (OF32) ((float*)Cout_)[(size_t)row * Nv + col] = val;
                else      ((unsigned short*)Cout_)[(size_t)row * Nv + col] = f2bf(val);
            }
        }
    }
}

// ---------------- deformable sampling, two-phase ----------------
__global__ __launch_bounds__(256) void sample_k(
        const unsigned short* __restrict__ v,    // (NB, HW, C) bf16
        const float* __restrict__ ref,           // (NB, Lq, 2) fp32
        const unsigned short* __restrict__ oa,   // (R, 96) bf16 = [off 64 | awl 32]
        unsigned short* __restrict__ samp) {     // (R, 256) bf16
    __shared__ int4   sidx[256];
    __shared__ float4 sw[256];

    int t = threadIdx.x;
    int row0 = blockIdx.x * 8;
    int n = blockIdx.x / (LQ / 8);

    {
        int q = t >> 5;
        int h = (t >> 2) & 7;
        int p = t & 3;
        int row = row0 + q;
        float refx = ref[row * 2 + 0];
        float refy = ref[row * 2 + 1];
        const unsigned short* oar = oa + (size_t)row * 96;
        float ox = bf2f(oar[(h * 4 + p) * 2 + 0]);
        float oy = bf2f(oar[(h * 4 + p) * 2 + 1]);
        float l  = bf2f(oar[64 + h * 4 + p]);
        float m = fmaxf(l, __shfl_xor(l, 1));
        m = fmaxf(m, __shfl_xor(m, 2));
        float e = __expf(l - m);
        float s = e + __shfl_xor(e, 1);
        s = s + __shfl_xor(s, 2);
        float wp = e / s;

        float gx = (refx + ox * (1.0f / WW)) * WW - 0.5f;
        float gy = (refy + oy * (1.0f / HH)) * HH - 0.5f;
        float fx = floorf(gx), fy = floorf(gy);
        float wx = gx - fx, wy = gy - fy;
        int x0 = (int)fx, y0 = (int)fy;
        int x1 = x0 + 1, y1 = y0 + 1;
        bool vx0 = (unsigned)x0 < WW, vx1 = (unsigned)x1 < WW;
        bool vy0 = (unsigned)y0 < HH, vy1 = (unsigned)y1 < HH;
        float w00 = (vx0 && vy0) ? wp * (1.f - wx) * (1.f - wy) : 0.f;
        float w10 = (vx1 && vy0) ? wp * wx * (1.f - wy)         : 0.f;
        float w01 = (vx0 && vy1) ? wp * (1.f - wx) * wy         : 0.f;
        float w11 = (vx1 && vy1) ? wp * wx * wy                 : 0.f;
        int cx0 = min(max(x0, 0), WW - 1), cx1 = min(max(x1, 0), WW - 1);
        int cy0 = min(max(y0, 0), HH - 1), cy1 = min(max(y1, 0), HH - 1);
        sidx[t] = (int4){cy0 * WW + cx0, cy0 * WW + cx1, cy1 * WW + cx0, cy1 * WW + cx1};
        sw[t]   = (float4){w00, w10, w01, w11};
    }
    __syncthreads();

    int q  = t >> 5;
    int sub = t & 31;
    int h  = sub >> 2;
    int cg = sub & 3;
    int row = row0 + q;
    const unsigned short* base = v + (size_t)n * HWSZ * CC + h * 32 + cg * 8;

    float acc[8];
    #pragma unroll
    for (int j = 0; j < 8; ++j) acc[j] = 0.f;

    #pragma unroll
    for (int p = 0; p < 4; ++p) {
        int e = ((q * 8 + h) * 4) + p;
        int4   I = sidx[e];
        float4 Wt = sw[e];
        const int* Ip = (const int*)&I;
        const float* Wp = (const float*)&Wt;
        #pragma unroll
        for (int c = 0; c < 4; ++c) {
            bf16x8 u = *(const bf16x8*)(base + (size_t)Ip[c] * CC);
            float wgt = Wp[c];
            #pragma unroll
            for (int j = 0; j < 8; ++j)
                acc[j] += wgt * bf2f((unsigned short)u[j]);
        }
    }

    bf16x8 o;
    #pragma unroll
    for (int j = 0; j < 8; ++j) o[j] = (short)f2bf(acc[j]);
    *(bf16x8*)(samp + (size_t)row * CC + h * 32 + cg * 8) = o;
}

// ---------------- fused LN2 + MLP: out = x2 + gelu(LN(x2)@W1+b1)@W2 + b2 ----------------
// Block = 32 rows, 256 thr (4 waves), grid 800. Hidden 1024 in 8 chunks of 128.
// LN2 fused at staging: 8 threads/row, shfl reduce, bf16 into fragment-major hblob.
// Stage1: mfma(A=W1frag, B=hfrag) -> D1[hidden][qrow]; gelu -> h1blob (LDS, b64 packs).
// Stage2: mfma(A=W2frag, B=h1frag) -> D2[c][qrow]; transpose via LDS; coalesced store.
// LDS strides 528/16=33 and 260/4=65 are odd -> conflict-free frag access (no xor).
__global__ __launch_bounds__(256) void mlp_k(
        const float* __restrict__ x2,            // (R,256) fp32 (LN2 input + residual)
        const float* __restrict__ lw,            // ln2 weight
        const float* __restrict__ lb,            // ln2 bias
        const unsigned short* __restrict__ w1s,  // swizzled (256x1024)
        const float* __restrict__ b1,
        const unsigned short* __restrict__ w2s,  // swizzled (1024x256)
        const float* __restrict__ b2,
        float* __restrict__ out) {
    __shared__ char lds_raw[33280];
    unsigned short* hblob  = (unsigned short*)lds_raw;            // 32 kq x 528 B
    unsigned short* h1blob = (unsigned short*)(lds_raw + 16896);  // 16 kq x 528 B
    float* trans = (float*)lds_raw;                               // alias (epilogue)

    int t = threadIdx.x;
    int lane = t & 63, wave = t >> 6;
    int quad = lane >> 4, l16 = lane & 15;
    int row0 = blockIdx.x * 32;

    // ---- fused LN2: 8 threads per row ----
    {
        int r = t >> 3, sub = t & 7;                 // r 0..31
        const float* xr = x2 + (size_t)(row0 + r) * CC;
        float4 xv[4][2];
        float s = 0.f, s2 = 0.f;
        #pragma unroll
        for (int jj = 0; jj < 4; ++jj) {
            #pragma unroll
            for (int u = 0; u < 2; ++u) {
                float4 v = *(const float4*)(xr + sub * 8 + jj * 64 + u * 4);
                xv[jj][u] = v;
                s  += v.x + v.y + v.z + v.w;
                s2 += v.x*v.x + v.y*v.y + v.z*v.z + v.w*v.w;
            }
        }
        #pragma unroll
        for (int m = 1; m < 8; m <<= 1) {            // 8-lane groups are wave-aligned
            s  += __shfl_xor(s,  m);
            s2 += __shfl_xor(s2, m);
        }
        float mean = s * (1.0f / CC);
        float var  = s2 * (1.0f / CC) - mean * mean;
        float rstd = rsqrtf(fmaxf(var, 0.0f) + 1e-5f);
        #pragma unroll
        for (int jj = 0; jj < 4; ++jj) {
            int c0 = sub * 8 + jj * 64;
            float4 w0 = *(const float4*)(lw + c0);
            float4 w1 = *(const float4*)(lw + c0 + 4);
            float4 bb0 = *(const float4*)(lb + c0);
            float4 bb1 = *(const float4*)(lb + c0 + 4);
            bf16x8 o;
            o[0] = (short)f2bf((xv[jj][0].x - mean) * rstd * w0.x + bb0.x);
            o[1] = (short)f2bf((xv[jj][0].y - mean) * rstd * w0.y + bb0.y);
            o[2] = (short)f2bf((xv[jj][0].z - mean) * rstd * w0.z + bb0.z);
            o[3] = (short)f2bf((xv[jj][0].w - mean) * rstd * w0.w + bb0.w);
            o[4] = (short)f2bf((xv[jj][1].x - mean) * rstd * w1.x + bb1.x);
            o[5] = (short)f2bf((xv[jj][1].y - mean) * rstd * w1.y + bb1.y);
            o[6] = (short)f2bf((xv[jj][1].z - mean) * rstd * w1.z + bb1.z);
            o[7] = (short)f2bf((xv[jj][1].w - mean) * rstd * w1.w + bb1.w);
            int kq = sub + jj * 8;                   // c0>>3
            *(bf16x8*)((char*)hblob + kq * 528 + r * 16) = o;
        }
    }
    __syncthreads();

    f32x4 acc2[4][2];    // [ct][qt]: c = wave*64+ct*16+quad*4+r, qrow = qt*16+l16
    #pragma unroll
    for (int a = 0; a < 4; ++a)
        #pragma unroll
        for (int b = 0; b < 2; ++b)
            acc2[a][b] = (f32x4){0.f, 0.f, 0.f, 0.f};

    for (int hc = 0; hc < 8; ++hc) {
        // ---- stage 1: this wave's 32 hidden of the 128-chunk ----
        f32x4 acc1[2][2];
        #pragma unroll
        for (int a = 0; a < 2; ++a)
            #pragma unroll
            for (int b = 0; b < 2; ++b)
                acc1[a][b] = (f32x4){0.f, 0.f, 0.f, 0.f};

        #pragma unroll
        for (int kb = 0; kb < 8; ++kb) {
            bf16x8 a1[2], b1f[2];
            #pragma unroll
            for (int ht = 0; ht < 2; ++ht) {
                int hh = hc * 128 + wave * 32 + ht * 16 + l16;
                a1[ht] = *(const bf16x8*)(w1s + ((size_t)(kb * 4 + quad) * 1024 + hh) * 8);
            }
            #pragma unroll
            for (int qt = 0; qt < 2; ++qt)
                b1f[qt] = *(const bf16x8*)((char*)hblob + (kb * 4 + quad) * 528 + (qt * 16 + l16) * 16);
            #pragma unroll
            for (int ht = 0; ht < 2; ++ht)
                #pragma unroll
                for (int qt = 0; qt < 2; ++qt)
                    acc1[ht][qt] = __builtin_amdgcn_mfma_f32_16x16x32_bf16(a1[ht], b1f[qt], acc1[ht][qt], 0, 0, 0);
        }

        // bias + exact gelu + pack 4 bf16 -> h1blob (b64, conflict-free)
        #pragma unroll
        for (int ht = 0; ht < 2; ++ht) {
            int hl = wave * 32 + ht * 16 + quad * 4;
            float4 bb = *(const float4*)(b1 + hc * 128 + hl);
            const float* bp = (const float*)&bb;
            #pragma unroll
            for (int qt = 0; qt < 2; ++qt) {
                unsigned long long pk = 0;
                #pragma unroll
                for (int r = 0; r < 4; ++r) {
                    float val = acc1[ht][qt][r] + bp[r];
                    val = 0.5f * val * (1.0f + erff(val * 0.70710678118654752f));
                    pk |= ((unsigned long long)f2bf(val)) << (16 * r);
                }
                int qrow = qt * 16 + l16;
                *(unsigned long long*)((char*)h1blob + (hl >> 3) * 528 + qrow * 16 + (hl & 7) * 2) = pk;
            }
        }
        __syncthreads();

        // ---- stage 2: acc2 += gelu_chunk @ W2[chunk rows] ----
        #pragma unroll
        for (int k2 = 0; k2 < 4; ++k2) {
            int kb2 = hc * 4 + k2;
            bf16x8 a2[4], b2f[2];
            #pragma unroll
            for (int ct = 0; ct < 4; ++ct) {
                int cc = wave * 64 + ct * 16 + l16;
                a2[ct] = *(const bf16x8*)(w2s + ((size_t)(kb2 * 4 + quad) * 256 + cc) * 8);
            }
            #pragma unroll
            for (int qt = 0; qt < 2; ++qt)
                b2f[qt] = *(const bf16x8*)((char*)h1blob + (k2 * 4 + quad) * 528 + (qt * 16 + l16) * 16);
            #pragma unroll
            for (int ct = 0; ct < 4; ++ct)
                #pragma unroll
                for (int qt = 0; qt < 2; ++qt)
                    acc2[ct][qt] = __builtin_amdgcn_mfma_f32_16x16x32_bf16(a2[ct], b2f[qt], acc2[ct][qt], 0, 0, 0);
        }
        __syncthreads();   // protects next chunk's h1blob writes (and final trans alias)
    }

    // ---- epilogue: transpose via LDS (odd-granule stride, no xor), residual, store ----
    #pragma unroll
    for (int qt = 0; qt < 2; ++qt) {
        int qrow = qt * 16 + l16;
        #pragma unroll
        for (int ct = 0; ct < 4; ++ct) {
            int c4 = wave * 16 + ct * 4 + quad;      // c/4, 0..63
            *(f32x4*)(trans + qrow * 260 + c4 * 4) = acc2[ct][qt];
        }
    }
    __syncthreads();
    {
        int rr = t >> 3;
        int c4b = t & 7;
        int row = row0 + rr;
        #pragma unroll
        for (int i = 0; i < 8; ++i) {
            int c4 = i * 8 + c4b;
            f32x4 v = *(const f32x4*)(trans + rr * 260 + c4 * 4);
            int c = c4 * 4;
            float4 xv = *(const float4*)(x2 + (size_t)row * CC + c);
            float4 bb = *(const float4*)(b2 + c);
            float4 o;
            o.x = v[0] + xv.x + bb.x;
            o.y = v[1] + xv.y + bb.y;
            o.z = v[2] + xv.z + bb.z;
            o.w = v[3] + xv.w + bb.w;
            *(float4*)(out + (size_t)row * CC + c) = o;
        }
    }
}

extern "C" void kernel_launch(void* const* d_in, const int* in_sizes, int n_in,
                              void* d_out, int out_size, void* d_ws, size_t ws_size,
                              hipStream_t stream) {
    const float* x     = (const float*)d_in[0];
    const float* ref   = (const float*)d_in[1];
    const float* value = (const float*)d_in[2];
    const float* ln1w  = (const float*)d_in[5];
    const float* ln1b  = (const float*)d_in[6];
    const float* ln2w  = (const float*)d_in[7];
    const float* ln2b  = (const float*)d_in[8];
    const float* Wv    = (const float*)d_in[9];
    const float* bv    = (const float*)d_in[10];
    const float* Woff  = (const float*)d_in[11];
    const float* boff  = (const float*)d_in[12];
    const float* Wa    = (const float*)d_in[13];
    const float* ba    = (const float*)d_in[14];
    const float* Wout  = (const float*)d_in[15];
    const float* bout  = (const float*)d_in[16];
    const float* W1    = (const float*)d_in[17];
    const float* b1    = (const float*)d_in[18];
    const float* W2    = (const float*)d_in[19];
    const float* b2    = (const float*)d_in[20];

    // ---- workspace layout (bytes), peak 84,935,168 ----
    char* ws = (char*)d_ws;
    unsigned short* wt_v  = (unsigned short*)(ws + 0);          // 131072
    unsigned short* wt_o  = (unsigned short*)(ws + 131072);     // 131072
    unsigned short* w1s_b = (unsigned short*)(ws + 262144);     // 524288 (swizzled)
    unsigned short* w2s_b = (unsigned short*)(ws + 786432);     // 524288 (swizzled)
    unsigned short* wt_oa = (unsigned short*)(ws + 1310720);    // 65536
    float*          b_oa  = (float*)         (ws + 1376256);    // 512
    float*          x2_f  = (float*)         (ws + 1376768);    // 26,214,400 (live to end)
    unsigned short* val_b = (unsigned short*)(ws + 40698368);   // 13,107,200
    unsigned short* smp_b = (unsigned short*)(ws + 40698368);   // overlays val_b
    unsigned short* xn_b  = (unsigned short*)(ws + 53805568);   // 13,107,200
    unsigned short* v_b   = (unsigned short*)(ws + 66912768);   // 13,107,200
    unsigned short* oa_b  = (unsigned short*)(ws + 80019968);   // 4,915,200

    // weight prep
    transpose_cvt_k<<<(256*256 + 255) / 256, 256, 0, stream>>>(Wv,   wt_v,           256, 256);
    transpose_cvt_k<<<(256*256 + 255) / 256, 256, 0, stream>>>(Wout, wt_o,           256, 256);
    transpose_cvt_k<<<(256*64  + 255) / 256, 256, 0, stream>>>(Woff, wt_oa,          256, 64);
    transpose_cvt_k<<<(256*32  + 255) / 256, 256, 0, stream>>>(Wa,   wt_oa + 64*256, 256, 32);
    swizzle_k<<<128, 256, 0, stream>>>(W1, w1s_b, 256, 1024);
    swizzle_k<<<128, 256, 0, stream>>>(W2, w2s_b, 1024, 256);
    bias_cat_k<<<1, 128, 0, stream>>>(boff, ba, b_oa);

    cvt_k<<<(RTOT*CC/4 + 255) / 256, 256, 0, stream>>>(value, val_b, RTOT*CC/4);
    ln_k<<<RTOT / 4, 256, 0, stream>>>(x, ln1w, ln1b, xn_b);

    dim3 blk(256);
    gemm_t<0, false><<<dim3(RTOT/128, 2), blk, 0, stream>>>(val_b, wt_v,  bv,   nullptr, v_b,  RTOT, 256,  256);
    gemm_t<0, false><<<dim3(RTOT/128, 1), blk, 0, stream>>>(xn_b,  wt_oa, b_oa, nullptr, oa_b, RTOT, 96,   256);
    sample_k<<<RTOT / 8, 256, 0, stream>>>(v_b, ref, oa_b, smp_b);
    gemm_t<2, true ><<<dim3(RTOT/128, 2), blk, 0, stream>>>(smp_b, wt_o,  bout, x,       x2_f, RTOT, 256,  256);
    // fused LN2 + MLP: out = x2 + gelu(LN(x2)@W1+b1)@W2 + b2
    mlp_k<<<RTOT / 32, blk, 0, stream>>>(x2_f, ln2w, ln2b, w1s_b, b1, w2s_b, b2, (float*)d_out);
}

// Round 7
// 248.314 us; speedup vs baseline: 1.2369x; 1.2369x over previous
//
#include <hip/hip_runtime.h>

// Problem constants (setup_inputs fixed: N=4, Lq=6400, C=256, H=W=80)
#define NB    4
#define LQ    6400
#define CC    256
#define HH    80
#define WW    80
#define HWSZ  (HH*WW)
#define RTOT  (NB*LQ)        // 25600 rows
#define HID   1024

typedef __attribute__((ext_vector_type(8))) short bf16x8;   // 8 bf16 = 4 VGPRs
typedef __attribute__((ext_vector_type(4))) float f32x4;

__device__ __forceinline__ float bf2f(unsigned short u) {
    unsigned int i = ((unsigned int)u) << 16;
    float f; __builtin_memcpy(&f, &i, 4); return f;
}
__device__ __forceinline__ unsigned short f2bf(float f) {
    unsigned int i; __builtin_memcpy(&i, &f, 4);
    unsigned int r = i + 0x7fffu + ((i >> 16) & 1u);   // RNE
    return (unsigned short)(r >> 16);
}

// ---------------- fp32 -> bf16 convert (4 elems/thread) ----------------
__global__ void cvt_k(const float* __restrict__ in, unsigned short* __restrict__ out, int n4) {
    int i = blockIdx.x * 256 + threadIdx.x;
    if (i < n4) {
        float4 u = ((const float4*)in)[i];
        ushort4 o;
        o.x = f2bf(u.x); o.y = f2bf(u.y); o.z = f2bf(u.z); o.w = f2bf(u.w);
        ((ushort4*)out)[i] = o;
    }
}

// ---------------- transpose + convert: Bt_bf16[n*K + k] = B_f32[k*N + n] ----------------
__global__ void transpose_cvt_k(const float* __restrict__ B,
                                unsigned short* __restrict__ Bt, int K, int N) {
    int idx = blockIdx.x * 256 + threadIdx.x;
    if (idx < K * N) {
        int n = idx / K;
        int k = idx - n * K;
        Bt[idx] = f2bf(B[k * N + n]);
    }
}

// ---------------- fragment-major weight swizzle ----------------
// dst group g (8 bf16): n = g%N, kq = g/N, kbase = (kq>>2)*32 + (kq&3)*8
// dst[g*8+j] = bf16(src[(kbase+j)*N + n]) — the exact VGPR image an A-fragment wants.
__global__ void swizzle_k(const float* __restrict__ src, unsigned short* __restrict__ dst,
                          int K, int N) {
    int g = blockIdx.x * 256 + threadIdx.x;
    if (g >= (K / 8) * N) return;
    int n  = g % N;
    int kq = g / N;
    int kbase = (kq >> 2) * 32 + (kq & 3) * 8;
    unsigned short* d = dst + (size_t)g * 8;
    #pragma unroll
    for (int j = 0; j < 8; ++j)
        d[j] = f2bf(src[(size_t)(kbase + j) * N + n]);
}

// ---------------- concat boff(64) + ba(32) into one fp32 bias[96] ----------------
__global__ void bias_cat_k(const float* __restrict__ boff, const float* __restrict__ ba,
                           float* __restrict__ out) {
    int i = threadIdx.x;
    if (i < 64) out[i] = boff[i];
    else if (i < 96) out[i] = ba[i - 64];
}

// ---------------- layernorm over C=256: fp32 in -> bf16 out; 1 wave/row ----------------
__global__ void ln_k(const float* __restrict__ x,
                     const float* __restrict__ w,
                     const float* __restrict__ b,
                     unsigned short* __restrict__ y) {
    int row  = blockIdx.x * 4 + (threadIdx.x >> 6);
    int lane = threadIdx.x & 63;
    const float* xr = x + (size_t)row * CC + lane * 4;
    float4 u = *(const float4*)xr;
    float s  = u.x + u.y + u.z + u.w;
    float s2 = u.x*u.x + u.y*u.y + u.z*u.z + u.w*u.w;
    #pragma unroll
    for (int m = 1; m < 64; m <<= 1) {
        s  += __shfl_xor(s,  m);
        s2 += __shfl_xor(s2, m);
    }
    float mean = s * (1.0f / CC);
    float var  = s2 * (1.0f / CC) - mean * mean;
    float rstd = rsqrtf(fmaxf(var, 0.0f) + 1e-5f);
    float4 uw = *(const float4*)(w + lane * 4);
    float4 ub = *(const float4*)(b + lane * 4);
    ushort4 o;
    o.x = f2bf((u.x - mean) * rstd * uw.x + ub.x);
    o.y = f2bf((u.y - mean) * rstd * uw.y + ub.y);
    o.z = f2bf((u.z - mean) * rstd * uw.z + ub.z);
    o.w = f2bf((u.w - mean) * rstd * uw.w + ub.w);
    *(ushort4*)(y + (size_t)row * CC + lane * 4) = o;
}

// ---------------- tiled GEMM: 64x128 block tile, 4 waves (2x2 of 32x64), BK=32 ----------
// global_load_lds width-16 staging, ds_read_b128 fragments, 8 MFMA/wave/ktile.
// EPI: 0=none, 2=add fp32 residual. OF32: fp32 out. M%64==0, K%32==0, Nv%16==0.
template<int EPI, bool OF32>
__global__ __launch_bounds__(256) void gemm_t(const unsigned short* __restrict__ A,
                                              const unsigned short* __restrict__ Bt,
                                              const float* __restrict__ bias,
                                              const float* __restrict__ res,
                                              void* __restrict__ Cout_,
                                              int M, int Nv, int K) {
    __shared__ unsigned short Als[64 * 32];
    __shared__ unsigned short Bls[128 * 32];
    int lane = threadIdx.x & 63;
    int wave = threadIdx.x >> 6;
    int quad = lane >> 4;
    int l16  = lane & 15;
    int m0 = blockIdx.x * 64;
    int n0 = blockIdx.y * 128;
    int wm = (wave & 1) * 32;
    int wn = (wave >> 1) * 64;

    f32x4 acc[2][4];
    #pragma unroll
    for (int i = 0; i < 2; ++i)
        #pragma unroll
        for (int j = 0; j < 4; ++j)
            acc[i][j] = (f32x4){0.f, 0.f, 0.f, 0.f};

    int srow = lane >> 2;
    int scol = (lane & 3) * 8;
    const unsigned short* Ag = A  + (size_t)(m0 + wave * 16 + srow) * K + scol;
    const unsigned short* Bg = Bt + (size_t)(n0 + wave * 32 + srow) * K + scol;
    unsigned short* Alp = &Als[wave * 512];
    unsigned short* Blp = &Bls[wave * 1024];

    for (int k0 = 0; k0 < K; k0 += 32) {
        __syncthreads();
        __builtin_amdgcn_global_load_lds(
            (const __attribute__((address_space(1))) void*)(Ag + k0),
            (__attribute__((address_space(3))) void*)Alp, 16, 0, 0);
        #pragma unroll
        for (int t = 0; t < 2; ++t) {
            __builtin_amdgcn_global_load_lds(
                (const __attribute__((address_space(1))) void*)(Bg + (size_t)t * 16 * K + k0),
                (__attribute__((address_space(3))) void*)(Blp + t * 512), 16, 0, 0);
        }
        __builtin_amdgcn_s_waitcnt(0);
        __syncthreads();

        bf16x8 af[2], bfr[4];
        #pragma unroll
        for (int i = 0; i < 2; ++i)
            af[i] = *(const bf16x8*)&Als[(wm + i * 16 + l16) * 32 + quad * 8];
        #pragma unroll
        for (int j = 0; j < 4; ++j)
            bfr[j] = *(const bf16x8*)&Bls[(wn + j * 16 + l16) * 32 + quad * 8];
        #pragma unroll
        for (int i = 0; i < 2; ++i)
            #pragma unroll
            for (int j = 0; j < 4; ++j)
                acc[i][j] = __builtin_amdgcn_mfma_f32_16x16x32_bf16(af[i], bfr[j], acc[i][j], 0, 0, 0);
    }

    #pragma unroll
    for (int j = 0; j < 4; ++j) {
        int cbase = n0 + wn + j * 16;
        if (cbase >= Nv) continue;                  // wave-uniform (Nv%16==0)
        int col = cbase + l16;
        float bv = bias[col];
        #pragma unroll
        for (int i = 0; i < 2; ++i) {
            #pragma unroll
            for (int r = 0; r < 4; ++r) {
                int row = m0 + wm + i * 16 + quad * 4 + r;
                float val = acc[i][j][r] + bv;
                if (EPI == 2) val += res[(size_t)row * Nv + col];
                if (OF32) ((float*)Cout_)[(size_t)row * Nv + col] = val;
                else      ((unsigned short*)Cout_)[(size_t)row * Nv + col] = f2bf(val);
            }
        }
    }
}

// ---------------- deformable sampling, two-phase ----------------
__global__ __launch_bounds__(256) void sample_k(
        const unsigned short* __restrict__ v,    // (NB, HW, C) bf16
        const float* __restrict__ ref,           // (NB, Lq, 2) fp32
        const unsigned short* __restrict__ oa,   // (R, 96) bf16 = [off 64 | awl 32]
        unsigned short* __restrict__ samp) {     // (R, 256) bf16
    __shared__ int4   sidx[256];
    __shared__ float4 sw[256];

    int t = threadIdx.x;
    int row0 = blockIdx.x * 8;
    int n = blockIdx.x / (LQ / 8);

    {
        int q = t >> 5;
        int h = (t >> 2) & 7;
        int p = t & 3;
        int row = row0 + q;
        float refx = ref[row * 2 + 0];
        float refy = ref[row * 2 + 1];
        const unsigned short* oar = oa + (size_t)row * 96;
        float ox = bf2f(oar[(h * 4 + p) * 2 + 0]);
        float oy = bf2f(oar[(h * 4 + p) * 2 + 1]);
        float l  = bf2f(oar[64 + h * 4 + p]);
        float m = fmaxf(l, __shfl_xor(l, 1));
        m = fmaxf(m, __shfl_xor(m, 2));
        float e = __expf(l - m);
        float s = e + __shfl_xor(e, 1);
        s = s + __shfl_xor(s, 2);
        float wp = e / s;

        float gx = (refx + ox * (1.0f / WW)) * WW - 0.5f;
        float gy = (refy + oy * (1.0f / HH)) * HH - 0.5f;
        float fx = floorf(gx), fy = floorf(gy);
        float wx = gx - fx, wy = gy - fy;
        int x0 = (int)fx, y0 = (int)fy;
        int x1 = x0 + 1, y1 = y0 + 1;
        bool vx0 = (unsigned)x0 < WW, vx1 = (unsigned)x1 < WW;
        bool vy0 = (unsigned)y0 < HH, vy1 = (unsigned)y1 < HH;
        float w00 = (vx0 && vy0) ? wp * (1.f - wx) * (1.f - wy) : 0.f;
        float w10 = (vx1 && vy0) ? wp * wx * (1.f - wy)         : 0.f;
        float w01 = (vx0 && vy1) ? wp * (1.f - wx) * wy         : 0.f;
        float w11 = (vx1 && vy1) ? wp * wx * wy                 : 0.f;
        int cx0 = min(max(x0, 0), WW - 1), cx1 = min(max(x1, 0), WW - 1);
        int cy0 = min(max(y0, 0), HH - 1), cy1 = min(max(y1, 0), HH - 1);
        sidx[t] = (int4){cy0 * WW + cx0, cy0 * WW + cx1, cy1 * WW + cx0, cy1 * WW + cx1};
        sw[t]   = (float4){w00, w10, w01, w11};
    }
    __syncthreads();

    int q  = t >> 5;
    int sub = t & 31;
    int h  = sub >> 2;
    int cg = sub & 3;
    int row = row0 + q;
    const unsigned short* base = v + (size_t)n * HWSZ * CC + h * 32 + cg * 8;

    float acc[8];
    #pragma unroll
    for (int j = 0; j < 8; ++j) acc[j] = 0.f;

    #pragma unroll
    for (int p = 0; p < 4; ++p) {
        int e = ((q * 8 + h) * 4) + p;
        int4   I = sidx[e];
        float4 Wt = sw[e];
        const int* Ip = (const int*)&I;
        const float* Wp = (const float*)&Wt;
        #pragma unroll
        for (int c = 0; c < 4; ++c) {
            bf16x8 u = *(const bf16x8*)(base + (size_t)Ip[c] * CC);
            float wgt = Wp[c];
            #pragma unroll
            for (int j = 0; j < 8; ++j)
                acc[j] += wgt * bf2f((unsigned short)u[j]);
        }
    }

    bf16x8 o;
    #pragma unroll
    for (int j = 0; j < 8; ++j) o[j] = (short)f2bf(acc[j]);
    *(bf16x8*)(samp + (size_t)row * CC + h * 32 + cg * 8) = o;
}

// ---------------- fused LN2 + MLP: out = x2 + gelu(LN(x2)@W1+b1)@W2 + b2 ----------------
// Block = 64 rows, 512 thr (8 waves), grid 400. Hidden 1024 in 8 chunks of 128.
// Stage1: wave w owns 16 hidden/chunk; mfma(A=W1frag, B=hfrag) -> gelu -> h1 blob.
// Stage2: wave w owns 32 out-cols;    mfma(A=W2frag, B=h1frag) -> acc2.
// Double-buffered h1 blob -> ONE barrier per chunk; stage2(hc) + stage1(hc+1)
// issue in the same barrier-free window (disjoint buffers) for ILP.
// LDS strides 1040 B (65 granules of 16B, odd) -> all frag accesses bank-uniform.
__global__ __launch_bounds__(512) void mlp_k(
        const float* __restrict__ x2,            // (R,256) fp32 (LN2 input + residual)
        const float* __restrict__ lw,
        const float* __restrict__ lb,
        const unsigned short* __restrict__ w1s,  // swizzled (256x1024)
        const float* __restrict__ b1,
        const unsigned short* __restrict__ w2s,  // swizzled (1024x256)
        const float* __restrict__ b2,
        float* __restrict__ out) {
    __shared__ char lds_raw[66560];
    unsigned short* hblob = (unsigned short*)lds_raw;            // 32 kq x 1040 B
    unsigned short* h1b0  = (unsigned short*)(lds_raw + 33280);  // 16 kq x 1040 B
    unsigned short* h1b1  = (unsigned short*)(lds_raw + 49920);  // 16 kq x 1040 B
    float* trans = (float*)lds_raw;                              // 64 x 260 dwords (epilogue alias)

    int t = threadIdx.x;
    int lane = t & 63, wave = t >> 6;
    int quad = lane >> 4, l16 = lane & 15;
    int row0 = blockIdx.x * 64;

    // ---- fused LN2: 8 threads per row, 64 rows ----
    {
        int r = t >> 3, sub = t & 7;
        const float* xr = x2 + (size_t)(row0 + r) * CC;
        float4 xv[4][2];
        float s = 0.f, s2 = 0.f;
        #pragma unroll
        for (int jj = 0; jj < 4; ++jj) {
            #pragma unroll
            for (int u = 0; u < 2; ++u) {
                float4 v = *(const float4*)(xr + sub * 8 + jj * 64 + u * 4);
                xv[jj][u] = v;
                s  += v.x + v.y + v.z + v.w;
                s2 += v.x*v.x + v.y*v.y + v.z*v.z + v.w*v.w;
            }
        }
        #pragma unroll
        for (int m = 1; m < 8; m <<= 1) {
            s  += __shfl_xor(s,  m);
            s2 += __shfl_xor(s2, m);
        }
        float mean = s * (1.0f / CC);
        float var  = s2 * (1.0f / CC) - mean * mean;
        float rstd = rsqrtf(fmaxf(var, 0.0f) + 1e-5f);
        #pragma unroll
        for (int jj = 0; jj < 4; ++jj) {
            int c0 = sub * 8 + jj * 64;
            float4 w0 = *(const float4*)(lw + c0);
            float4 w1 = *(const float4*)(lw + c0 + 4);
            float4 bb0 = *(const float4*)(lb + c0);
            float4 bb1 = *(const float4*)(lb + c0 + 4);
            bf16x8 o;
            o[0] = (short)f2bf((xv[jj][0].x - mean) * rstd * w0.x + bb0.x);
            o[1] = (short)f2bf((xv[jj][0].y - mean) * rstd * w0.y + bb0.y);
            o[2] = (short)f2bf((xv[jj][0].z - mean) * rstd * w0.z + bb0.z);
            o[3] = (short)f2bf((xv[jj][0].w - mean) * rstd * w0.w + bb0.w);
            o[4] = (short)f2bf((xv[jj][1].x - mean) * rstd * w1.x + bb1.x);
            o[5] = (short)f2bf((xv[jj][1].y - mean) * rstd * w1.y + bb1.y);
            o[6] = (short)f2bf((xv[jj][1].z - mean) * rstd * w1.z + bb1.z);
            o[7] = (short)f2bf((xv[jj][1].w - mean) * rstd * w1.w + bb1.w);
            int kq = sub + jj * 8;
            *(bf16x8*)((char*)hblob + kq * 1040 + r * 16) = o;
        }
    }
    __syncthreads();

    f32x4 acc2[2][4];    // [ct][qt]: c = wave*32+ct*16+quad*4+r, qrow = qt*16+l16
    #pragma unroll
    for (int a = 0; a < 2; ++a)
        #pragma unroll
        for (int b = 0; b < 4; ++b)
            acc2[a][b] = (f32x4){0.f, 0.f, 0.f, 0.f};

    auto s1 = [&](int hc, unsigned short* dst) {
        f32x4 a[4];
        #pragma unroll
        for (int qt = 0; qt < 4; ++qt) a[qt] = (f32x4){0.f, 0.f, 0.f, 0.f};
        #pragma unroll
        for (int kb = 0; kb < 8; ++kb) {
            bf16x8 a1 = *(const bf16x8*)(w1s + ((size_t)(kb * 4 + quad) * 1024 + hc * 128 + wave * 16 + l16) * 8);
            #pragma unroll
            for (int qt = 0; qt < 4; ++qt) {
                bf16x8 bf = *(const bf16x8*)((char*)hblob + (kb * 4 + quad) * 1040 + (qt * 16 + l16) * 16);
                a[qt] = __builtin_amdgcn_mfma_f32_16x16x32_bf16(a1, bf, a[qt], 0, 0, 0);
            }
        }
        int hl = wave * 16 + quad * 4;               // hidden local in chunk, 0..127
        float4 bb = *(const float4*)(b1 + hc * 128 + hl);
        const float* bp = (const float*)&bb;
        #pragma unroll
        for (int qt = 0; qt < 4; ++qt) {
            unsigned long long pk = 0;
            #pragma unroll
            for (int r = 0; r < 4; ++r) {
                float val = a[qt][r] + bp[r];
                val = 0.5f * val * (1.0f + erff(val * 0.70710678118654752f));
                pk |= ((unsigned long long)f2bf(val)) << (16 * r);
            }
            *(unsigned long long*)((char*)dst + (hl >> 3) * 1040 + (qt * 16 + l16) * 16 + (hl & 7) * 2) = pk;
        }
    };

    auto s2 = [&](int hc, const unsigned short* src) {
        #pragma unroll
        for (int k2 = 0; k2 < 4; ++k2) {
            bf16x8 a2[2], bf[4];
            #pragma unroll
            for (int ct = 0; ct < 2; ++ct)
                a2[ct] = *(const bf16x8*)(w2s + ((size_t)((hc * 4 + k2) * 4 + quad) * 256 + wave * 32 + ct * 16 + l16) * 8);
            #pragma unroll
            for (int qt = 0; qt < 4; ++qt)
                bf[qt] = *(const bf16x8*)((const char*)src + (k2 * 4 + quad) * 1040 + (qt * 16 + l16) * 16);
            #pragma unroll
            for (int ct = 0; ct < 2; ++ct)
                #pragma unroll
                for (int qt = 0; qt < 4; ++qt)
                    acc2[ct][qt] = __builtin_amdgcn_mfma_f32_16x16x32_bf16(a2[ct], bf[qt], acc2[ct][qt], 0, 0, 0);
        }
    };

    s1(0, h1b0);
    for (int hc = 0; hc < 8; ++hc) {
        __syncthreads();
        const unsigned short* cur = (hc & 1) ? h1b1 : h1b0;
        unsigned short*       nxt = (hc & 1) ? h1b0 : h1b1;
        s2(hc, cur);
        if (hc < 7) s1(hc + 1, nxt);
    }
    __syncthreads();

    // ---- epilogue: transpose via LDS, add x2 + b2, coalesced 128B stores ----
    #pragma unroll
    for (int qt = 0; qt < 4; ++qt) {
        int qrow = qt * 16 + l16;
        #pragma unroll
        for (int ct = 0; ct < 2; ++ct) {
            int c4 = wave * 8 + ct * 4 + quad;       // c/4 index, 0..63
            *(f32x4*)(trans + qrow * 260 + c4 * 4) = acc2[ct][qt];
        }
    }
    __syncthreads();
    {
        int rr = t >> 3;                              // 0..63
        int c4b = t & 7;
        int row = row0 + rr;
        #pragma unroll
        for (int i = 0; i < 8; ++i) {
            int c4 = i * 8 + c4b;
            f32x4 v = *(const f32x4*)(trans + rr * 260 + c4 * 4);
            int c = c4 * 4;
            float4 xv = *(const float4*)(x2 + (size_t)row * CC + c);
            float4 bb = *(const float4*)(b2 + c);
            float4 o;
            o.x = v[0] + xv.x + bb.x;
            o.y = v[1] + xv.y + bb.y;
            o.z = v[2] + xv.z + bb.z;
            o.w = v[3] + xv.w + bb.w;
            *(float4*)(out + (size_t)row * CC + c) = o;
        }
    }
}

extern "C" void kernel_launch(void* const* d_in, const int* in_sizes, int n_in,
                              void* d_out, int out_size, void* d_ws, size_t ws_size,
                              hipStream_t stream) {
    const float* x     = (const float*)d_in[0];
    const float* ref   = (const float*)d_in[1];
    const float* value = (const float*)d_in[2];
    const float* ln1w  = (const float*)d_in[5];
    const float* ln1b  = (const float*)d_in[6];
    const float* ln2w  = (const float*)d_in[7];
    const float* ln2b  = (const float*)d_in[8];
    const float* Wv    = (const float*)d_in[9];
    const float* bv    = (const float*)d_in[10];
    const float* Woff  = (const float*)d_in[11];
    const float* boff  = (const float*)d_in[12];
    const float* Wa    = (const float*)d_in[13];
    const float* ba    = (const float*)d_in[14];
    const float* Wout  = (const float*)d_in[15];
    const float* bout  = (const float*)d_in[16];
    const float* W1    = (const float*)d_in[17];
    const float* b1    = (const float*)d_in[18];
    const float* W2    = (const float*)d_in[19];
    const float* b2    = (const float*)d_in[20];

    // ---- workspace layout (bytes), peak 84,935,168 ----
    char* ws = (char*)d_ws;
    unsigned short* wt_v  = (unsigned short*)(ws + 0);          // 131072
    unsigned short* wt_o  = (unsigned short*)(ws + 131072);     // 131072
    unsigned short* w1s_b = (unsigned short*)(ws + 262144);     // 524288 (swizzled)
    unsigned short* w2s_b = (unsigned short*)(ws + 786432);     // 524288 (swizzled)
    unsigned short* wt_oa = (unsigned short*)(ws + 1310720);    // 65536
    float*          b_oa  = (float*)         (ws + 1376256);    // 512
    float*          x2_f  = (float*)         (ws + 1376768);    // 26,214,400 (live to end)
    unsigned short* val_b = (unsigned short*)(ws + 40698368);   // 13,107,200
    unsigned short* smp_b = (unsigned short*)(ws + 40698368);   // overlays val_b
    unsigned short* xn_b  = (unsigned short*)(ws + 53805568);   // 13,107,200
    unsigned short* v_b   = (unsigned short*)(ws + 66912768);   // 13,107,200
    unsigned short* oa_b  = (unsigned short*)(ws + 80019968);   // 4,915,200

    // weight prep
    transpose_cvt_k<<<(256*256 + 255) / 256, 256, 0, stream>>>(Wv,   wt_v,           256, 256);
    transpose_cvt_k<<<(256*256 + 255) / 256, 256, 0, stream>>>(Wout, wt_o,           256, 256);
    transpose_cvt_k<<<(256*64  + 255) / 256, 256, 0, stream>>>(Woff, wt_oa,          256, 64);
    transpose_cvt_k<<<(256*32  + 255) / 256, 256, 0, stream>>>(Wa,   wt_oa + 64*256, 256, 32);
    swizzle_k<<<128, 256, 0, stream>>>(W1, w1s_b, 256, 1024);
    swizzle_k<<<128, 256, 0, stream>>>(W2, w2s_b, 1024, 256);
    bias_cat_k<<<1, 128, 0, stream>>>(boff, ba, b_oa);

    cvt_k<<<(RTOT*CC/4 + 255) / 256, 256, 0, stream>>>(value, val_b, RTOT*CC/4);
    ln_k<<<RTOT / 4, 256, 0, stream>>>(x, ln1w, ln1b, xn_b);

    dim3 blk(256);
    gemm_t<0, false><<<dim3(RTOT/64, 2), blk, 0, stream>>>(val_b, wt_v,  bv,   nullptr, v_b,  RTOT, 256,  256);
    gemm_t<0, false><<<dim3(RTOT/64, 1), blk, 0, stream>>>(xn_b,  wt_oa, b_oa, nullptr, oa_b, RTOT, 96,   256);
    sample_k<<<RTOT / 8, 256, 0, stream>>>(v_b, ref, oa_b, smp_b);
    gemm_t<2, true ><<<dim3(RTOT/64, 2), blk, 0, stream>>>(smp_b, wt_o,  bout, x,       x2_f, RTOT, 256,  256);
    // fused LN2 + MLP
    mlp_k<<<RTOT / 64, 512, 0, stream>>>(x2_f, ln2w, ln2b, w1s_b, b1, w2s_b, b2, (float*)d_out);
}

// Round 8
// 224.553 us; speedup vs baseline: 1.3678x; 1.1058x over previous
//
#include <hip/hip_runtime.h>

// Problem constants (setup_inputs fixed: N=4, Lq=6400, C=256, H=W=80)
#define NB    4
#define LQ    6400
#define CC    256
#define HH    80
#define WW    80
#define HWSZ  (HH*WW)
#define RTOT  (NB*LQ)        // 25600 rows
#define HID   1024

typedef __attribute__((ext_vector_type(8))) short bf16x8;   // 8 bf16 = 4 VGPRs
typedef __attribute__((ext_vector_type(4))) float f32x4;

__device__ __forceinline__ float bf2f(unsigned short u) {
    unsigned int i = ((unsigned int)u) << 16;
    float f; __builtin_memcpy(&f, &i, 4); return f;
}
__device__ __forceinline__ unsigned short f2bf(float f) {
    unsigned int i; __builtin_memcpy(&i, &f, 4);
    unsigned int r = i + 0x7fffu + ((i >> 16) & 1u);   // RNE
    return (unsigned short)(r >> 16);
}

// ---------------- fp32 -> bf16 convert (4 elems/thread) ----------------
__global__ void cvt_k(const float* __restrict__ in, unsigned short* __restrict__ out, int n4) {
    int i = blockIdx.x * 256 + threadIdx.x;
    if (i < n4) {
        float4 u = ((const float4*)in)[i];
        ushort4 o;
        o.x = f2bf(u.x); o.y = f2bf(u.y); o.z = f2bf(u.z); o.w = f2bf(u.w);
        ((ushort4*)out)[i] = o;
    }
}

// ---------------- one-shot weight prep (transpose + fragment swizzles + bias cat) ------
// swizzle layout: group g -> n = g%N, kq = g/N, kbase = (kq>>2)*32 + (kq&3)*8;
// dst[g*8+j] = bf16(src[(kbase+j)*N + n])  — the exact VGPR image an A-fragment wants.
__global__ void prep_k(const float* __restrict__ Wv,   const float* __restrict__ Wout,
                       const float* __restrict__ W1,   const float* __restrict__ W2,
                       const float* __restrict__ Woff, const float* __restrict__ Wa,
                       const float* __restrict__ boff, const float* __restrict__ ba,
                       unsigned short* __restrict__ wtv,  unsigned short* __restrict__ woutS,
                       unsigned short* __restrict__ w1s,  unsigned short* __restrict__ w2s,
                       unsigned short* __restrict__ woas, float* __restrict__ b_oa) {
    int idx = blockIdx.x * 256 + threadIdx.x;
    if (idx < 65536) {                          // wtv transpose: wtv[n*256+k] = Wv[k*256+n]
        int n = idx >> 8, k = idx & 255;
        wtv[idx] = f2bf(Wv[(size_t)k * 256 + n]);
        return;
    }
    idx -= 65536;
    if (idx < 32768) {                          // w1s swizzle (K=256, N=1024)
        int n = idx & 1023, kq = idx >> 10;
        int kb = (kq >> 2) * 32 + (kq & 3) * 8;
        unsigned short* d = w1s + (size_t)idx * 8;
        #pragma unroll
        for (int j = 0; j < 8; ++j) d[j] = f2bf(W1[(size_t)(kb + j) * 1024 + n]);
        return;
    }
    idx -= 32768;
    if (idx < 32768) {                          // w2s swizzle (K=1024, N=256)
        int n = idx & 255, kq = idx >> 8;
        int kb = (kq >> 2) * 32 + (kq & 3) * 8;
        unsigned short* d = w2s + (size_t)idx * 8;
        #pragma unroll
        for (int j = 0; j < 8; ++j) d[j] = f2bf(W2[(size_t)(kb + j) * 256 + n]);
        return;
    }
    idx -= 32768;
    if (idx < 8192) {                           // woutS swizzle (K=256, N=256)
        int n = idx & 255, kq = idx >> 8;
        int kb = (kq >> 2) * 32 + (kq & 3) * 8;
        unsigned short* d = woutS + (size_t)idx * 8;
        #pragma unroll
        for (int j = 0; j < 8; ++j) d[j] = f2bf(Wout[(size_t)(kb + j) * 256 + n]);
        return;
    }
    idx -= 8192;
    if (idx < 4096) {                           // woas swizzle (K=256, Npad=128: Woff|Wa|0)
        int n = idx & 127, kq = idx >> 7;
        int kb = (kq >> 2) * 32 + (kq & 3) * 8;
        unsigned short* d = woas + (size_t)idx * 8;
        #pragma unroll
        for (int j = 0; j < 8; ++j) {
            float v = 0.f;
            if (n < 64)      v = Woff[(size_t)(kb + j) * 64 + n];
            else if (n < 96) v = Wa[(size_t)(kb + j) * 32 + (n - 64)];
            d[j] = f2bf(v);
        }
        return;
    }
    idx -= 4096;
    if (idx < 96) b_oa[idx] = idx < 64 ? boff[idx] : ba[idx - 64];
}

// ---------------- shared LN stage: 64 rows fp32 -> fragment-major bf16 hblob ----------
// 512 threads: 8 threads/row; hblob 32 kq x 1040 B stride (odd 16B-granule -> bank-clean).
__device__ __forceinline__ void ln_stage(const float* __restrict__ xbase,  // + row0*CC
                                         const float* __restrict__ lw,
                                         const float* __restrict__ lb,
                                         unsigned short* hblob, int t) {
    int r = t >> 3, sub = t & 7;
    const float* xr = xbase + (size_t)r * CC;
    float4 xv[4][2];
    float s = 0.f, s2 = 0.f;
    #pragma unroll
    for (int jj = 0; jj < 4; ++jj) {
        #pragma unroll
        for (int u = 0; u < 2; ++u) {
            float4 v = *(const float4*)(xr + sub * 8 + jj * 64 + u * 4);
            xv[jj][u] = v;
            s  += v.x + v.y + v.z + v.w;
            s2 += v.x*v.x + v.y*v.y + v.z*v.z + v.w*v.w;
        }
    }
    #pragma unroll
    for (int m = 1; m < 8; m <<= 1) {
        s  += __shfl_xor(s,  m);
        s2 += __shfl_xor(s2, m);
    }
    float mean = s * (1.0f / CC);
    float var  = s2 * (1.0f / CC) - mean * mean;
    float rstd = rsqrtf(fmaxf(var, 0.0f) + 1e-5f);
    #pragma unroll
    for (int jj = 0; jj < 4; ++jj) {
        int c0 = sub * 8 + jj * 64;
        float4 w0 = *(const float4*)(lw + c0);
        float4 w1 = *(const float4*)(lw + c0 + 4);
        float4 bb0 = *(const float4*)(lb + c0);
        float4 bb1 = *(const float4*)(lb + c0 + 4);
        bf16x8 o;
        o[0] = (short)f2bf((xv[jj][0].x - mean) * rstd * w0.x + bb0.x);
        o[1] = (short)f2bf((xv[jj][0].y - mean) * rstd * w0.y + bb0.y);
        o[2] = (short)f2bf((xv[jj][0].z - mean) * rstd * w0.z + bb0.z);
        o[3] = (short)f2bf((xv[jj][0].w - mean) * rstd * w0.w + bb0.w);
        o[4] = (short)f2bf((xv[jj][1].x - mean) * rstd * w1.x + bb1.x);
        o[5] = (short)f2bf((xv[jj][1].y - mean) * rstd * w1.y + bb1.y);
        o[6] = (short)f2bf((xv[jj][1].z - mean) * rstd * w1.z + bb1.z);
        o[7] = (short)f2bf((xv[jj][1].w - mean) * rstd * w1.w + bb1.w);
        int kq = sub + jj * 8;
        *(bf16x8*)((char*)hblob + kq * 1040 + r * 16) = o;
    }
}

// ---------------- tiled GEMM: 64x128 block tile (value projection) ----------------
template<int EPI, bool OF32>
__global__ __launch_bounds__(256) void gemm_t(const unsigned short* __restrict__ A,
                                              const unsigned short* __restrict__ Bt,
                                              const float* __restrict__ bias,
                                              const float* __restrict__ res,
                                              void* __restrict__ Cout_,
                                              int M, int Nv, int K) {
    __shared__ unsigned short Als[64 * 32];
    __shared__ unsigned short Bls[128 * 32];
    int lane = threadIdx.x & 63;
    int wave = threadIdx.x >> 6;
    int quad = lane >> 4;
    int l16  = lane & 15;
    int m0 = blockIdx.x * 64;
    int n0 = blockIdx.y * 128;
    int wm = (wave & 1) * 32;
    int wn = (wave >> 1) * 64;

    f32x4 acc[2][4];
    #pragma unroll
    for (int i = 0; i < 2; ++i)
        #pragma unroll
        for (int j = 0; j < 4; ++j)
            acc[i][j] = (f32x4){0.f, 0.f, 0.f, 0.f};

    int srow = lane >> 2;
    int scol = (lane & 3) * 8;
    const unsigned short* Ag = A  + (size_t)(m0 + wave * 16 + srow) * K + scol;
    const unsigned short* Bg = Bt + (size_t)(n0 + wave * 32 + srow) * K + scol;
    unsigned short* Alp = &Als[wave * 512];
    unsigned short* Blp = &Bls[wave * 1024];

    for (int k0 = 0; k0 < K; k0 += 32) {
        __syncthreads();
        __builtin_amdgcn_global_load_lds(
            (const __attribute__((address_space(1))) void*)(Ag + k0),
            (__attribute__((address_space(3))) void*)Alp, 16, 0, 0);
        #pragma unroll
        for (int t = 0; t < 2; ++t) {
            __builtin_amdgcn_global_load_lds(
                (const __attribute__((address_space(1))) void*)(Bg + (size_t)t * 16 * K + k0),
                (__attribute__((address_space(3))) void*)(Blp + t * 512), 16, 0, 0);
        }
        __builtin_amdgcn_s_waitcnt(0);
        __syncthreads();

        bf16x8 af[2], bfr[4];
        #pragma unroll
        for (int i = 0; i < 2; ++i)
            af[i] = *(const bf16x8*)&Als[(wm + i * 16 + l16) * 32 + quad * 8];
        #pragma unroll
        for (int j = 0; j < 4; ++j)
            bfr[j] = *(const bf16x8*)&Bls[(wn + j * 16 + l16) * 32 + quad * 8];
        #pragma unroll
        for (int i = 0; i < 2; ++i)
            #pragma unroll
            for (int j = 0; j < 4; ++j)
                acc[i][j] = __builtin_amdgcn_mfma_f32_16x16x32_bf16(af[i], bfr[j], acc[i][j], 0, 0, 0);
    }

    #pragma unroll
    for (int j = 0; j < 4; ++j) {
        int cbase = n0 + wn + j * 16;
        if (cbase >= Nv) continue;
        int col = cbase + l16;
        float bv = bias[col];
        #pragma unroll
        for (int i = 0; i < 2; ++i) {
            #pragma unroll
            for (int r = 0; r < 4; ++r) {
                int row = m0 + wm + i * 16 + quad * 4 + r;
                float val = acc[i][j][r] + bv;
                if (EPI == 2) val += res[(size_t)row * Nv + col];
                if (OF32) ((float*)Cout_)[(size_t)row * Nv + col] = val;
                else      ((unsigned short*)Cout_)[(size_t)row * Nv + col] = f2bf(val);
            }
        }
    }
}

// ---------------- fused LN1 + offsets/logits GEMM: oa = LN(x) @ [Woff|Wa] + b ---------
// Block = 64 rows, 512 thr, grid 400. A = woas (fragment-swizzled, Npad=128, valid 96).
// Waves 0..5 each own 16 output cols; D[n=quad*4+r][qrow=l16]; b64 stores.
__global__ __launch_bounds__(512) void lnoa_k(
        const float* __restrict__ x, const float* __restrict__ lw, const float* __restrict__ lb,
        const unsigned short* __restrict__ woas, const float* __restrict__ b_oa,
        unsigned short* __restrict__ oa) {
    __shared__ char lds_raw[33280];
    unsigned short* hblob = (unsigned short*)lds_raw;
    int t = threadIdx.x;
    int lane = t & 63, wave = t >> 6;
    int quad = lane >> 4, l16 = lane & 15;
    int row0 = blockIdx.x * 64;

    ln_stage(x + (size_t)row0 * CC, lw, lb, hblob, t);
    __syncthreads();

    if (wave < 6) {
        f32x4 acc[4];
        #pragma unroll
        for (int qt = 0; qt < 4; ++qt) acc[qt] = (f32x4){0.f, 0.f, 0.f, 0.f};
        #pragma unroll
        for (int kb = 0; kb < 8; ++kb) {
            bf16x8 a1 = *(const bf16x8*)(woas + ((size_t)(kb * 4 + quad) * 128 + wave * 16 + l16) * 8);
            #pragma unroll
            for (int qt = 0; qt < 4; ++qt) {
                bf16x8 bf = *(const bf16x8*)((char*)hblob + (kb * 4 + quad) * 1040 + (qt * 16 + l16) * 16);
                acc[qt] = __builtin_amdgcn_mfma_f32_16x16x32_bf16(a1, bf, acc[qt], 0, 0, 0);
            }
        }
        int n0 = wave * 16 + quad * 4;
        float4 bb = *(const float4*)(b_oa + n0);
        const float* bp = (const float*)&bb;
        #pragma unroll
        for (int qt = 0; qt < 4; ++qt) {
            unsigned long long pk = 0;
            #pragma unroll
            for (int r = 0; r < 4; ++r)
                pk |= ((unsigned long long)f2bf(acc[qt][r] + bp[r])) << (16 * r);
            *(unsigned long long*)(oa + (size_t)(row0 + qt * 16 + l16) * 96 + n0) = pk;
        }
    }
}

// ---------------- fused sampling + Wout GEMM + residual: x2 = x + samp@Wout + bout -----
// Block = 64 queries, 512 thr, grid 400 (batch = blockIdx/100).
// Per 32-row half: phase A (softmax+bilinear weights/indices -> LDS),
// phase B (16x bf16x8 gathers -> fragment-major hblob). Then K=256 MFMA with
// woutS as A-operand; epilogue transposes via LDS (2 passes of 32 rows).
__global__ __launch_bounds__(512) void samwout_k(
        const unsigned short* __restrict__ v,    // (NB, HW, C) bf16
        const float* __restrict__ ref,           // (R, 2) fp32
        const unsigned short* __restrict__ oa,   // (R, 96) bf16
        const unsigned short* __restrict__ woutS,
        const float* __restrict__ bout,
        const float* __restrict__ x,             // residual fp32
        float* __restrict__ x2) {
    __shared__ char lds_raw[57856];
    unsigned short* hblob = (unsigned short*)lds_raw;            // 32 kq x 1040 B
    short4* sidx = (short4*)(lds_raw + 33280);                   // 1024 x 8 B
    float4* sw   = (float4*)(lds_raw + 41472);                   // 1024 x 16 B
    float* trans = (float*)lds_raw;                              // alias (epilogue, 32x260)

    int t = threadIdx.x;
    int lane = t & 63, wave = t >> 6;
    int quad = lane >> 4, l16 = lane & 15;
    int row0 = blockIdx.x * 64;
    int nb = blockIdx.x / (LQ / 64);             // batch, block-uniform

    for (int half = 0; half < 2; ++half) {
        int rbase = half * 32;
        // ---- phase A: 1024 tuples (32q x 8h x 4p), 2 per thread ----
        #pragma unroll
        for (int s = 0; s < 2; ++s) {
            int e = t + s * 512;
            int q = e >> 5, sub = e & 31, h = sub >> 2, p = sub & 3;
            int row = row0 + rbase + q;
            float refx = ref[row * 2 + 0];
            float refy = ref[row * 2 + 1];
            const unsigned short* oar = oa + (size_t)row * 96;
            float ox = bf2f(oar[(h * 4 + p) * 2 + 0]);
            float oy = bf2f(oar[(h * 4 + p) * 2 + 1]);
            float l  = bf2f(oar[64 + h * 4 + p]);
            float m = fmaxf(l, __shfl_xor(l, 1));
            m = fmaxf(m, __shfl_xor(m, 2));
            float ee = __expf(l - m);
            float ss = ee + __shfl_xor(ee, 1);
            ss = ss + __shfl_xor(ss, 2);
            float wp = ee / ss;

            float gx = (refx + ox * (1.0f / WW)) * WW - 0.5f;
            float gy = (refy + oy * (1.0f / HH)) * HH - 0.5f;
            float fx = floorf(gx), fy = floorf(gy);
            float wx = gx - fx, wy = gy - fy;
            int x0 = (int)fx, y0 = (int)fy;
            int x1 = x0 + 1, y1 = y0 + 1;
            bool vx0 = (unsigned)x0 < WW, vx1 = (unsigned)x1 < WW;
            bool vy0 = (unsigned)y0 < HH, vy1 = (unsigned)y1 < HH;
            float w00 = (vx0 && vy0) ? wp * (1.f - wx) * (1.f - wy) : 0.f;
            float w10 = (vx1 && vy0) ? wp * wx * (1.f - wy)         : 0.f;
            float w01 = (vx0 && vy1) ? wp * (1.f - wx) * wy         : 0.f;
            float w11 = (vx1 && vy1) ? wp * wx * wy                 : 0.f;
            int cx0 = min(max(x0, 0), WW - 1), cx1 = min(max(x1, 0), WW - 1);
            int cy0 = min(max(y0, 0), HH - 1), cy1 = min(max(y1, 0), HH - 1);
            sidx[e] = (short4){(short)(cy0 * WW + cx0), (short)(cy0 * WW + cx1),
                               (short)(cy1 * WW + cx0), (short)(cy1 * WW + cx1)};
            sw[e]   = (float4){w00, w10, w01, w11};
        }
        __syncthreads();
        // ---- phase B: gather, 2 (q,h,cg) combos per thread ----
        #pragma unroll
        for (int s = 0; s < 2; ++s) {
            int c = t + s * 512;
            int q = c >> 5, sub = c & 31, h = sub >> 2, cg = sub & 3;
            const unsigned short* base = v + (size_t)nb * HWSZ * CC + h * 32 + cg * 8;
            float acc[8];
            #pragma unroll
            for (int j = 0; j < 8; ++j) acc[j] = 0.f;
            #pragma unroll
            for (int p = 0; p < 4; ++p) {
                int e = q * 32 + h * 4 + p;
                short4 I = sidx[e];
                float4 Wt = sw[e];
                const short* Ip = (const short*)&I;
                const float* Wp = (const float*)&Wt;
                #pragma unroll
                for (int cn = 0; cn < 4; ++cn) {
                    bf16x8 u = *(const bf16x8*)(base + (size_t)(unsigned short)Ip[cn] * CC);
                    float wgt = Wp[cn];
                    #pragma unroll
                    for (int j = 0; j < 8; ++j)
                        acc[j] += wgt * bf2f((unsigned short)u[j]);
                }
            }
            bf16x8 o;
            #pragma unroll
            for (int j = 0; j < 8; ++j) o[j] = (short)f2bf(acc[j]);
            *(bf16x8*)((char*)hblob + sub * 1040 + (rbase + q) * 16) = o;
        }
        __syncthreads();
    }

    // ---- Wout MFMA: K=256, 8 waves x 32 cols ----
    f32x4 acc2[2][4];
    #pragma unroll
    for (int a = 0; a < 2; ++a)
        #pragma unroll
        for (int b = 0; b < 4; ++b)
            acc2[a][b] = (f32x4){0.f, 0.f, 0.f, 0.f};
    #pragma unroll
    for (int kb = 0; kb < 8; ++kb) {
        bf16x8 a2[2], bf[4];
        #pragma unroll
        for (int ct = 0; ct < 2; ++ct)
            a2[ct] = *(const bf16x8*)(woutS + ((size_t)(kb * 4 + quad) * 256 + wave * 32 + ct * 16 + l16) * 8);
        #pragma unroll
        for (int qt = 0; qt < 4; ++qt)
            bf[qt] = *(const bf16x8*)((char*)hblob + (kb * 4 + quad) * 1040 + (qt * 16 + l16) * 16);
        #pragma unroll
        for (int ct = 0; ct < 2; ++ct)
            #pragma unroll
            for (int qt = 0; qt < 4; ++qt)
                acc2[ct][qt] = __builtin_amdgcn_mfma_f32_16x16x32_bf16(a2[ct], bf[qt], acc2[ct][qt], 0, 0, 0);
    }

    // ---- epilogue: transpose via LDS (2 passes of 32 rows), + x + bout, store x2 ----
    for (int p = 0; p < 2; ++p) {
        __syncthreads();
        #pragma unroll
        for (int qi = 0; qi < 2; ++qi) {
            int qt = p * 2 + qi;
            int qlocal = qt * 16 + l16 - p * 32;
            #pragma unroll
            for (int ct = 0; ct < 2; ++ct) {
                int c4 = wave * 8 + ct * 4 + quad;
                *(f32x4*)(trans + qlocal * 260 + c4 * 4) = acc2[ct][qt];
            }
        }
        __syncthreads();
        int rr = t >> 4;                          // 0..31
        int c4b = t & 15;
        int row = row0 + p * 32 + rr;
        #pragma unroll
        for (int i = 0; i < 4; ++i) {
            int c4 = i * 16 + c4b;
            f32x4 vv = *(const f32x4*)(trans + rr * 260 + c4 * 4);
            int c = c4 * 4;
            float4 xv = *(const float4*)(x + (size_t)row * CC + c);
            float4 bb = *(const float4*)(bout + c);
            float4 o;
            o.x = vv[0] + xv.x + bb.x;
            o.y = vv[1] + xv.y + bb.y;
            o.z = vv[2] + xv.z + bb.z;
            o.w = vv[3] + xv.w + bb.w;
            *(float4*)(x2 + (size_t)row * CC + c) = o;
        }
    }
}

// ---------------- fused LN2 + MLP: out = x2 + gelu(LN(x2)@W1+b1)@W2 + b2 ----------------
__global__ __launch_bounds__(512) void mlp_k(
        const float* __restrict__ x2,
        const float* __restrict__ lw,
        const float* __restrict__ lb,
        const unsigned short* __restrict__ w1s,  // swizzled (256x1024)
        const float* __restrict__ b1,
        const unsigned short* __restrict__ w2s,  // swizzled (1024x256)
        const float* __restrict__ b2,
        float* __restrict__ out) {
    __shared__ char lds_raw[66560];
    unsigned short* hblob = (unsigned short*)lds_raw;            // 32 kq x 1040 B
    unsigned short* h1b0  = (unsigned short*)(lds_raw + 33280);  // 16 kq x 1040 B
    unsigned short* h1b1  = (unsigned short*)(lds_raw + 49920);  // 16 kq x 1040 B
    float* trans = (float*)lds_raw;                              // epilogue alias

    int t = threadIdx.x;
    int lane = t & 63, wave = t >> 6;
    int quad = lane >> 4, l16 = lane & 15;
    int row0 = blockIdx.x * 64;

    ln_stage(x2 + (size_t)row0 * CC, lw, lb, hblob, t);
    __syncthreads();

    f32x4 acc2[2][4];
    #pragma unroll
    for (int a = 0; a < 2; ++a)
        #pragma unroll
        for (int b = 0; b < 4; ++b)
            acc2[a][b] = (f32x4){0.f, 0.f, 0.f, 0.f};

    auto s1 = [&](int hc, unsigned short* dst) {
        f32x4 a[4];
        #pragma unroll
        for (int qt = 0; qt < 4; ++qt) a[qt] = (f32x4){0.f, 0.f, 0.f, 0.f};
        #pragma unroll
        for (int kb = 0; kb < 8; ++kb) {
            bf16x8 a1 = *(const bf16x8*)(w1s + ((size_t)(kb * 4 + quad) * 1024 + hc * 128 + wave * 16 + l16) * 8);
            #pragma unroll
            for (int qt = 0; qt < 4; ++qt) {
                bf16x8 bf = *(const bf16x8*)((char*)hblob + (kb * 4 + quad) * 1040 + (qt * 16 + l16) * 16);
                a[qt] = __builtin_amdgcn_mfma_f32_16x16x32_bf16(a1, bf, a[qt], 0, 0, 0);
            }
        }
        int hl = wave * 16 + quad * 4;
        float4 bb = *(const float4*)(b1 + hc * 128 + hl);
        const float* bp = (const float*)&bb;
        #pragma unroll
        for (int qt = 0; qt < 4; ++qt) {
            unsigned long long pk = 0;
            #pragma unroll
            for (int r = 0; r < 4; ++r) {
                float val = a[qt][r] + bp[r];
                val = 0.5f * val * (1.0f + erff(val * 0.70710678118654752f));
                pk |= ((unsigned long long)f2bf(val)) << (16 * r);
            }
            *(unsigned long long*)((char*)dst + (hl >> 3) * 1040 + (qt * 16 + l16) * 16 + (hl & 7) * 2) = pk;
        }
    };

    auto s2 = [&](int hc, const unsigned short* src) {
        #pragma unroll
        for (int k2 = 0; k2 < 4; ++k2) {
            bf16x8 a2[2], bf[4];
            #pragma unroll
            for (int ct = 0; ct < 2; ++ct)
                a2[ct] = *(const bf16x8*)(w2s + ((size_t)((hc * 4 + k2) * 4 + quad) * 256 + wave * 32 + ct * 16 + l16) * 8);
            #pragma unroll
            for (int qt = 0; qt < 4; ++qt)
                bf[qt] = *(const bf16x8*)((const char*)src + (k2 * 4 + quad) * 1040 + (qt * 16 + l16) * 16);
            #pragma unroll
            for (int ct = 0; ct < 2; ++ct)
                #pragma unroll
                for (int qt = 0; qt < 4; ++qt)
                    acc2[ct][qt] = __builtin_amdgcn_mfma_f32_16x16x32_bf16(a2[ct], bf[qt], acc2[ct][qt], 0, 0, 0);
        }
    };

    s1(0, h1b0);
    for (int hc = 0; hc < 8; ++hc) {
        __syncthreads();
        const unsigned short* cur = (hc & 1) ? h1b1 : h1b0;
        unsigned short*       nxt = (hc & 1) ? h1b0 : h1b1;
        s2(hc, cur);
        if (hc < 7) s1(hc + 1, nxt);
    }
    __syncthreads();

    #pragma unroll
    for (int qt = 0; qt < 4; ++qt) {
        int qrow = qt * 16 + l16;
        #pragma unroll
        for (int ct = 0; ct < 2; ++ct) {
            int c4 = wave * 8 + ct * 4 + quad;
            *(f32x4*)(trans + qrow * 260 + c4 * 4) = acc2[ct][qt];
        }
    }
    __syncthreads();
    {
        int rr = t >> 3;
        int c4b = t & 7;
        int row = row0 + rr;
        #pragma unroll
        for (int i = 0; i < 8; ++i) {
            int c4 = i * 8 + c4b;
            f32x4 v = *(const f32x4*)(trans + rr * 260 + c4 * 4);
            int c = c4 * 4;
            float4 xv = *(const float4*)(x2 + (size_t)row * CC + c);
            float4 bb = *(const float4*)(b2 + c);
            float4 o;
            o.x = v[0] + xv.x + bb.x;
            o.y = v[1] + xv.y + bb.y;
            o.z = v[2] + xv.z + bb.z;
            o.w = v[3] + xv.w + bb.w;
            *(float4*)(out + (size_t)row * CC + c) = o;
        }
    }
}

extern "C" void kernel_launch(void* const* d_in, const int* in_sizes, int n_in,
                              void* d_out, int out_size, void* d_ws, size_t ws_size,
                              hipStream_t stream) {
    const float* x     = (const float*)d_in[0];
    const float* ref   = (const float*)d_in[1];
    const float* value = (const float*)d_in[2];
    const float* ln1w  = (const float*)d_in[5];
    const float* ln1b  = (const float*)d_in[6];
    const float* ln2w  = (const float*)d_in[7];
    const float* ln2b  = (const float*)d_in[8];
    const float* Wv    = (const float*)d_in[9];
    const float* bv    = (const float*)d_in[10];
    const float* Woff  = (const float*)d_in[11];
    const float* boff  = (const float*)d_in[12];
    const float* Wa    = (const float*)d_in[13];
    const float* ba    = (const float*)d_in[14];
    const float* Wout  = (const float*)d_in[15];
    const float* bout  = (const float*)d_in[16];
    const float* W1    = (const float*)d_in[17];
    const float* b1    = (const float*)d_in[18];
    const float* W2    = (const float*)d_in[19];
    const float* b2    = (const float*)d_in[20];

    // ---- workspace layout (bytes), peak ~58.7 MB ----
    char* ws = (char*)d_ws;
    unsigned short* wtv_b  = (unsigned short*)(ws + 0);          // 131072
    unsigned short* wouts_b= (unsigned short*)(ws + 131072);     // 131072
    unsigned short* w1s_b  = (unsigned short*)(ws + 262144);     // 524288
    unsigned short* w2s_b  = (unsigned short*)(ws + 786432);     // 524288
    unsigned short* woas_b = (unsigned short*)(ws + 1310720);    // 65536
    float*          b_oa   = (float*)         (ws + 1376256);    // 512
    float*          x2_f   = (float*)         (ws + 1376768);    // 26,214,400
    unsigned short* val_b  = (unsigned short*)(ws + 27591168);   // 13,107,200
    unsigned short* v_b    = (unsigned short*)(ws + 40698368);   // 13,107,200
    unsigned short* oa_b   = (unsigned short*)(ws + 53805568);   // 4,915,200 -> 58,720,768

    // one-shot weight prep (transpose + swizzles + bias concat)
    prep_k<<<561, 256, 0, stream>>>(Wv, Wout, W1, W2, Woff, Wa, boff, ba,
                                    wtv_b, wouts_b, w1s_b, w2s_b, woas_b, b_oa);
    // value fp32 -> bf16
    cvt_k<<<(RTOT*CC/4 + 255) / 256, 256, 0, stream>>>(value, val_b, RTOT*CC/4);
    // value projection -> v_b
    gemm_t<0, false><<<dim3(RTOT/64, 2), 256, 0, stream>>>(val_b, wtv_b, bv, nullptr, v_b, RTOT, 256, 256);
    // fused LN1 + offsets/logits -> oa_b
    lnoa_k<<<RTOT/64, 512, 0, stream>>>(x, ln1w, ln1b, woas_b, b_oa, oa_b);
    // fused sampling + Wout + residual(x) -> x2
    samwout_k<<<RTOT/64, 512, 0, stream>>>(v_b, ref, oa_b, wouts_b, bout, x, x2_f);
    // fused LN2 + MLP -> out
    mlp_k<<<RTOT/64, 512, 0, stream>>>(x2_f, ln2w, ln2b, w1s_b, b1, w2s_b, b2, (float*)d_out);
}